// Round 6
// baseline (735.148 us; speedup 1.0000x reference)
//
#include <hip/hip_runtime.h>

#define B_SZ 2048
#define HID  1024
#define G4   4096
#define IN_D 512
#define T_LEN 20

// Tile swizzle: 16B chunk q of row r stored at q ^ ((r>>1)&3) -> b128 frag
// reads land 8 banks x 2-way (free, m136); DMA writes stay linear.
#define POFF(r, q) ((r)*32 + ((((q) ^ (((r) >> 1) & 3))) << 3))

typedef __attribute__((ext_vector_type(8))) _Float16 f16x8;
typedef __attribute__((ext_vector_type(4))) float f32x4;
typedef const __attribute__((address_space(1))) void* gas_p;
typedef __attribute__((address_space(3))) void* las_p;

__device__ __forceinline__ float bf2f(ushort u){
  union { unsigned int i; float f; } v; v.i = ((unsigned int)u) << 16; return v.f;
}
__device__ __forceinline__ ushort f2bf(float f){
  union { float f; unsigned int i; } v; v.f = f;
  unsigned int r = v.i + 0x7fffu + ((v.i >> 16) & 1u);
  return (ushort)(r >> 16);
}
// fp16 RTN. All tensor magnitudes here (|h|<=1, |W|~0.03, |c0|~N(0,1)) are far
// inside fp16 range; rel err 2^-11 beats bf16's 2^-9.
__device__ __forceinline__ ushort f2h(float f){
  _Float16 h = (_Float16)f;
  union { _Float16 h; ushort u; } v; v.h = h; return v.u;
}
__device__ __forceinline__ float rdv(const void* p, long idx, int fl){
  return fl ? ((const float*)p)[idx] : bf2f(((const ushort*)p)[idx]);
}
__device__ __forceinline__ float sigm(float x){ return 1.0f/(1.0f + __expf(-x)); }
__device__ __forceinline__ float tanh_f(float x){
  float e = __expf(2.0f*x);
  return 1.0f - 2.0f/(e + 1.0f);
}

// flag=1 -> fp32 inputs; flag=0 -> bf16.
__global__ void detect_dtype(const ushort* __restrict__ h0bits, int* __restrict__ flag){
  int weird = 0;
  for (int i = 0; i < 256; i += 2){
    float a = fabsf(bf2f(h0bits[i]));
    if (!(a >= 1e-8f && a <= 1e4f)) weird++;
  }
  *flag = (weird >= 32) ? 1 : 0;
}

// Packed+swizzled fp16 layouts (every wave-level access = dense span):
//   h: tile (mb*32+kt) of 4096 halfs, element (b&127, j&31) at POFF
//   W: tile (nb*32+kt) of 4096 halfs, row r = g*32+(j&31)
__global__ void canon(const void* __restrict__ h0, const void* __restrict__ c0,
                      const void* __restrict__ whh, const int* __restrict__ flag,
                      ushort* __restrict__ hA,
                      float* __restrict__ c_state,
                      ushort* __restrict__ wpk){
  const int fl = *flag;
  long i = (long)blockIdx.x * 256 + threadIdx.x;
  const long N1 = (long)B_SZ * HID;
  const long N3 = (long)G4 * HID;
  if (i < N1){
    const int b = (int)(i >> 10), j = (int)(i & 1023);
    const int r = b & 127, q = (j >> 3) & 3;
    const long po = ((long)(b >> 7)*32 + (j >> 5))*4096 + POFF(r, q) + (j & 7);
    hA[po] = f2h(rdv(h0, i, fl));
    return;
  }
  i -= N1;
  if (i < N1){ c_state[i] = rdv(c0, i, fl); return; }
  i -= N1;
  if (i < N3){
    const int n = (int)(i >> 10), k = (int)(i & 1023);
    const int g = n >> 10, j = n & 1023;
    const int nb = j >> 5, r = g*32 + (j & 31);
    const int kt = k >> 5, q = (k >> 3) & 3;
    const long base = ((long)(nb*32 + kt))*4096 + POFF(r, q) + (k & 7);
    wpk[base] = f2h(rdv(whh, i, fl));
  }
}

// Fold embedding + input GEMM + biases into exact rank-2 update:
// gates_x[t,b,n] = obs[t,b,0]*M0[n] + obs[t,b,1]*M1[n] + Beff[n]
__global__ void fold_emb(const void* __restrict__ Wih, const void* __restrict__ Wemb,
                         const void* __restrict__ bemb, const void* __restrict__ bih,
                         const void* __restrict__ bhh, const int* __restrict__ flag,
                         float* __restrict__ M0, float* __restrict__ M1, float* __restrict__ Beff){
  const int n = blockIdx.x;
  const int lane = threadIdx.x;
  const int fl = *flag;
  float s0 = 0.f, s1 = 0.f, sb = 0.f;
  for (int j = lane; j < IN_D; j += 64){
    float w  = rdv(Wih, (long)n*IN_D + j, fl);
    float e0 = rdv(Wemb, 2L*j, fl);
    float e1 = rdv(Wemb, 2L*j + 1, fl);
    float be = rdv(bemb, j, fl);
    s0 += w*e0; s1 += w*e1; sb += w*be;
  }
  #pragma unroll
  for (int off = 32; off > 0; off >>= 1){
    s0 += __shfl_down(s0, off, 64);
    s1 += __shfl_down(s1, off, 64);
    sb += __shfl_down(sb, off, 64);
  }
  if (lane == 0){
    M0[n] = s0; M1[n] = s1;
    Beff[n] = sb + rdv(bih, n, fl) + rdv(bhh, n, fl);
  }
}

// R4 (654us) + A off the LDS port: A frags load global->VGPR directly (packed
// layout = dense per-lane dwordx4), register ping-pong one K-iter ahead (named
// sets, no runtime indexing -> no scratch). B(W) keeps DMA->LDS (4x wave
// broadcast). R3's version of this failed ONLY because its XCD map put all of
// A (8MB) in every XCD's L2; R4's map gives each XCD A 2MB + W 2MB = resident.
// Per-CU/iter LDS traffic 96KB -> 48KB (565 cyc), below the MFMA floor
// (620 cyc). The barrier's vmcnt(0) drain fences both the B DMA and the A
// register loads issued in the previous iter.
// R5 bug fixed here: LDS is B-only, so offB has NO +4096 base (R5 kept R4's
// offset into a buffer half that no longer exists -> OOB LDS reads -> NaN).
__global__ __launch_bounds__(256, 2)
void lstm_step(const ushort* __restrict__ hin, ushort* __restrict__ hout,
               void* __restrict__ out_final,
               float* __restrict__ c_state,
               const ushort* __restrict__ wpk,
               const float* __restrict__ M0, const float* __restrict__ M1,
               const float* __restrict__ Beff,
               const void* __restrict__ obs_raw, int t_step,
               const int* __restrict__ flag, int is_final)
{
  // B-only dbuf: 2 x 4096 halfs = 16 KB. buf k at lds[k*4096 .. +4095].
  __shared__ __align__(16) ushort lds[2*4096];

  const int tid  = threadIdx.x;
  const int wave = tid >> 6;
  const int lane = tid & 63;
  const int l15  = lane & 15;
  const int quad = lane >> 4;
  const int wm   = wave & 1;    // M half (64 rows)
  const int wn   = wave >> 1;   // j half (16 cols of each gate)

  // XCD partition: xcd x owns mb in {(x&1)*8 + 0..7}, nb in {(x>>1)*8 + 0..7}
  const int bid = blockIdx.x;
  const int xcd = bid & 7, u = bid >> 3;
  const int mb  = ((xcd & 1) << 3) | (u & 7);       // 0..15
  const int nb  = ((xcd >> 1) << 3) | (u >> 3);     // 0..31
  const int n0  = nb << 5;

  f32x4 acc[4][4];   // [gate][mt]
  #pragma unroll
  for (int g = 0; g < 4; g++)
    #pragma unroll
    for (int mt = 0; mt < 4; mt++)
      acc[g][mt] = (f32x4){0.f, 0.f, 0.f, 0.f};

  const ushort* aB = hin + (size_t)mb*32*4096;
  const ushort* wB = wpk + (size_t)nb*32*4096;

  const int dOff = tid*8;   // halfs; 256 thr x 16B = 4KB per instr

  #define DMA_B(kt, buf) do {                                                 \
    const ushort* s1 = wB + (size_t)(kt)*4096;                                \
    ushort* d = &lds[(buf)*4096];                                             \
    __builtin_amdgcn_global_load_lds((gas_p)(s1+dOff),      (las_p)(d+dOff),      16,0,0); \
    __builtin_amdgcn_global_load_lds((gas_p)(s1+2048+dOff), (las_p)(d+2048+dOff), 16,0,0); \
  } while (0)

  // kt-invariant swizzled frag offsets (halfs)
  int offA[4], offB[4];
  #pragma unroll
  for (int mt = 0; mt < 4; mt++) {
    const int r = wm*64 + mt*16 + l15;             // 0..127
    offA[mt] = POFF(r, quad);
  }
  #pragma unroll
  for (int g = 0; g < 4; g++) {
    const int r = g*32 + wn*16 + l15;              // 0..127
    offB[g] = POFF(r, quad);                       // B-only LDS: no base offset
  }

  // prologue: A(0) -> set0 regs, B(0) -> buf0
  f16x8 a0[4], a1[4];
  #pragma unroll
  for (int mt = 0; mt < 4; mt++)
    a0[mt] = *reinterpret_cast<const f16x8*>(aB + offA[mt]);
  DMA_B(0, 0);

  // One K-step: uses CUR regs + lds[kt&1]; prefetches kt+1 into NXT regs.
  #define KSTEP(kt, CUR, NXT) do {                                            \
    __syncthreads();   /* vmcnt(0): B(kt) in LDS, A(kt) in CUR regs */        \
    if ((kt) + 1 < HID/32) {                                                  \
      DMA_B((kt)+1, ((kt)+1) & 1);                                            \
      const ushort* an = aB + (size_t)((kt)+1)*4096;                          \
      NXT[0] = *reinterpret_cast<const f16x8*>(an + offA[0]);                 \
      NXT[1] = *reinterpret_cast<const f16x8*>(an + offA[1]);                 \
      NXT[2] = *reinterpret_cast<const f16x8*>(an + offA[2]);                 \
      NXT[3] = *reinterpret_cast<const f16x8*>(an + offA[3]);                 \
    }                                                                         \
    const int sb_ = ((kt) & 1) * 4096;                                        \
    f16x8 b[4];                                                               \
    _Pragma("unroll")                                                         \
    for (int g = 0; g < 4; g++)                                               \
      b[g] = *reinterpret_cast<const f16x8*>(&lds[sb_ + offB[g]]);            \
    _Pragma("unroll")                                                         \
    for (int g = 0; g < 4; g++)                                               \
      _Pragma("unroll")                                                       \
      for (int mt = 0; mt < 4; mt++)                                          \
        acc[g][mt] = __builtin_amdgcn_mfma_f32_16x16x32_f16(CUR[mt], b[g], acc[g][mt], 0, 0, 0); \
  } while (0)

  #pragma unroll 1
  for (int kt2 = 0; kt2 < HID/64; kt2++) {
    KSTEP(2*kt2,     a0, a1);
    KSTEP(2*kt2 + 1, a1, a0);
  }
  #undef KSTEP
  #undef DMA_B

  // Epilogue: fused LSTM cell. C/D layout: col = lane&15, row = quad*4 + reg.
  const int fl = *flag;
  const int j = n0 + wn*16 + l15;
  float bi[4], m0v[4], m1v[4];
  #pragma unroll
  for (int g = 0; g < 4; g++) {
    bi[g]  = Beff[g*HID + j];
    m0v[g] = M0[g*HID + j];
    m1v[g] = M1[g*HID + j];
  }
  const int jq = (j >> 3) & 3;   // k-chunk of col j in next step's packed h
  #pragma unroll
  for (int mt = 0; mt < 4; mt++) {
    #pragma unroll
    for (int r = 0; r < 4; r++) {
      const int bl7 = wm*64 + mt*16 + quad*4 + r;   // b & 127
      const int b   = mb*128 + bl7;
      const long oidx = ((long)t_step * B_SZ + b) * 2;
      const float o0 = rdv(obs_raw, oidx, fl);
      const float o1 = rdv(obs_raw, oidx + 1, fl);
      const size_t off = (size_t)b*HID + j;
      float pi = acc[0][mt][r] + o0*m0v[0] + o1*m1v[0] + bi[0];
      float pf = acc[1][mt][r] + o0*m0v[1] + o1*m1v[1] + bi[1];
      float pg = acc[2][mt][r] + o0*m0v[2] + o1*m1v[2] + bi[2];
      float po = acc[3][mt][r] + o0*m0v[3] + o1*m1v[3] + bi[3];
      float cn = sigm(pf)*c_state[off] + sigm(pi)*tanh_f(pg);
      float hn = sigm(po)*tanh_f(cn);
      c_state[off] = cn;
      if (is_final) {
        if (fl) ((float*)out_final)[off] = hn;
        else    ((ushort*)out_final)[off] = f2bf(hn);
      } else {
        const long hpo = ((long)mb*32 + (j >> 5))*4096 + POFF(bl7, jq) + (j & 7);
        hout[hpo] = f2h(hn);
      }
    }
  }
}

extern "C" void kernel_launch(void* const* d_in, const int* in_sizes, int n_in,
                              void* d_out, int out_size, void* d_ws, size_t ws_size,
                              hipStream_t stream) {
  const void* obs  = d_in[0];
  const void* h0   = d_in[1];
  const void* c0   = d_in[2];
  const void* Wemb = d_in[3];
  const void* bemb = d_in[4];
  const void* Wih  = d_in[5];
  const void* Whh  = d_in[6];
  const void* bih  = d_in[7];
  const void* bhh  = d_in[8];

  char* w = (char*)d_ws;
  int*    flag    = (int*)w;
  float*  M0      = (float*)(w + 256);
  float*  M1      = M0 + G4;
  float*  Beff    = M1 + G4;
  float*  c_state = Beff + G4;                              // 8 MB
  ushort* wpk     = (ushort*)(c_state + (size_t)B_SZ*HID);  // 8 MB packed W (fp16)
  ushort* hA      = wpk + (size_t)G4*HID;                   // 4 MB
  ushort* hB      = hA + (size_t)B_SZ*HID;                  // 4 MB  (~24 MB total)

  detect_dtype<<<1, 1, 0, stream>>>((const ushort*)h0, flag);

  long totalCanon = 2L*B_SZ*HID + (long)G4*HID;
  canon<<<(int)((totalCanon + 255)/256), 256, 0, stream>>>(
      h0, c0, Whh, flag, hA, c_state, wpk);

  fold_emb<<<G4, 64, 0, stream>>>(Wih, Wemb, bemb, bih, bhh, flag, M0, M1, Beff);

  for (int t = 0; t < T_LEN; t++) {
    const ushort* ih = (t & 1) ? hB : hA;
    ushort* oh = (t & 1) ? hA : hB;
    lstm_step<<<512, 256, 0, stream>>>(ih, oh, d_out, c_state,
                                       wpk, M0, M1, Beff,
                                       obs, t, flag, (t == T_LEN - 1) ? 1 : 0);
  }
}

// Round 7
// 692.028 us; speedup vs baseline: 1.0623x; 1.0623x over previous
//
#include <hip/hip_runtime.h>

#define B_SZ 2048
#define HID  1024
#define G4   4096
#define IN_D 512
#define T_LEN 20

// Tile swizzle: 16B chunk q of row r stored at q ^ ((r>>1)&3) -> b128 frag
// reads land 8 banks x 2-way (free, m136); DMA writes stay linear.
#define POFF(r, q) ((r)*32 + ((((q) ^ (((r) >> 1) & 3))) << 3))

typedef __attribute__((ext_vector_type(8))) _Float16 f16x8;
typedef __attribute__((ext_vector_type(4))) float f32x4;
typedef const __attribute__((address_space(1))) void* gas_p;
typedef __attribute__((address_space(3))) void* las_p;

__device__ __forceinline__ float bf2f(ushort u){
  union { unsigned int i; float f; } v; v.i = ((unsigned int)u) << 16; return v.f;
}
__device__ __forceinline__ ushort f2bf(float f){
  union { float f; unsigned int i; } v; v.f = f;
  unsigned int r = v.i + 0x7fffu + ((v.i >> 16) & 1u);
  return (ushort)(r >> 16);
}
// fp16 RTN. All tensor magnitudes here (|h|<=1, |W|~0.03, |c0|~N(0,1)) are far
// inside fp16 range; rel err 2^-11 beats bf16's 2^-9.
__device__ __forceinline__ ushort f2h(float f){
  _Float16 h = (_Float16)f;
  union { _Float16 h; ushort u; } v; v.h = h; return v.u;
}
__device__ __forceinline__ float rdv(const void* p, long idx, int fl){
  return fl ? ((const float*)p)[idx] : bf2f(((const ushort*)p)[idx]);
}
__device__ __forceinline__ float sigm(float x){ return 1.0f/(1.0f + __expf(-x)); }
__device__ __forceinline__ float tanh_f(float x){
  float e = __expf(2.0f*x);
  return 1.0f - 2.0f/(e + 1.0f);
}

// flag=1 -> fp32 inputs; flag=0 -> bf16.
__global__ void detect_dtype(const ushort* __restrict__ h0bits, int* __restrict__ flag){
  int weird = 0;
  for (int i = 0; i < 256; i += 2){
    float a = fabsf(bf2f(h0bits[i]));
    if (!(a >= 1e-8f && a <= 1e4f)) weird++;
  }
  *flag = (weird >= 32) ? 1 : 0;
}

// Packed+swizzled fp16 layouts (every wave-level access = dense span):
//   h: tile (mb*32+kt) of 4096 halfs, element (b&127, j&31) at POFF
//   W: tile (nb*32+kt) of 4096 halfs, row r = g*32+(j&31)
// Consecutive kt tiles are contiguous -> a BK=64 stage is one 8KB linear span.
__global__ void canon(const void* __restrict__ h0, const void* __restrict__ c0,
                      const void* __restrict__ whh, const int* __restrict__ flag,
                      ushort* __restrict__ hA,
                      float* __restrict__ c_state,
                      ushort* __restrict__ wpk){
  const int fl = *flag;
  long i = (long)blockIdx.x * 256 + threadIdx.x;
  const long N1 = (long)B_SZ * HID;
  const long N3 = (long)G4 * HID;
  if (i < N1){
    const int b = (int)(i >> 10), j = (int)(i & 1023);
    const int r = b & 127, q = (j >> 3) & 3;
    const long po = ((long)(b >> 7)*32 + (j >> 5))*4096 + POFF(r, q) + (j & 7);
    hA[po] = f2h(rdv(h0, i, fl));
    return;
  }
  i -= N1;
  if (i < N1){ c_state[i] = rdv(c0, i, fl); return; }
  i -= N1;
  if (i < N3){
    const int n = (int)(i >> 10), k = (int)(i & 1023);
    const int g = n >> 10, j = n & 1023;
    const int nb = j >> 5, r = g*32 + (j & 31);
    const int kt = k >> 5, q = (k >> 3) & 3;
    const long base = ((long)(nb*32 + kt))*4096 + POFF(r, q) + (k & 7);
    wpk[base] = f2h(rdv(whh, i, fl));
  }
}

// Fold embedding + input GEMM + biases into exact rank-2 update:
// gates_x[t,b,n] = obs[t,b,0]*M0[n] + obs[t,b,1]*M1[n] + Beff[n]
__global__ void fold_emb(const void* __restrict__ Wih, const void* __restrict__ Wemb,
                         const void* __restrict__ bemb, const void* __restrict__ bih,
                         const void* __restrict__ bhh, const int* __restrict__ flag,
                         float* __restrict__ M0, float* __restrict__ M1, float* __restrict__ Beff){
  const int n = blockIdx.x;
  const int lane = threadIdx.x;
  const int fl = *flag;
  float s0 = 0.f, s1 = 0.f, sb = 0.f;
  for (int j = lane; j < IN_D; j += 64){
    float w  = rdv(Wih, (long)n*IN_D + j, fl);
    float e0 = rdv(Wemb, 2L*j, fl);
    float e1 = rdv(Wemb, 2L*j + 1, fl);
    float be = rdv(bemb, j, fl);
    s0 += w*e0; s1 += w*e1; sb += w*be;
  }
  #pragma unroll
  for (int off = 32; off > 0; off >>= 1){
    s0 += __shfl_down(s0, off, 64);
    s1 += __shfl_down(s1, off, 64);
    sb += __shfl_down(sb, off, 64);
  }
  if (lane == 0){
    M0[n] = s0; M1[n] = s1;
    Beff[n] = sb + rdv(bih, n, fl) + rdv(bhh, n, fl);
  }
}

// R4 (654us, 32us/step) with BK 32->64: identical operands-through-DMA->LDS
// structure (R3/R6 refuted per-lane A-global loads twice), but 16 iterations
// instead of 32 -> the ~700cyc/iter fixed barrier exposure (drain+lgkm+convoy
// re-form) is paid half as often. LDS 64KB/block = 2 bufs x [A 16K | B 16K];
// grid 512 = 2 blocks/CU (LDS cap 160/64 = 2). k accumulation order unchanged
// -> bit-identical output vs R4.
__global__ __launch_bounds__(256, 2)
void lstm_step(const ushort* __restrict__ hin, ushort* __restrict__ hout,
               void* __restrict__ out_final,
               float* __restrict__ c_state,
               const ushort* __restrict__ wpk,
               const float* __restrict__ M0, const float* __restrict__ M1,
               const float* __restrict__ Beff,
               const void* __restrict__ obs_raw, int t_step,
               const int* __restrict__ flag, int is_final)
{
  // [buf][A0 4096 | A1 4096 | B0 4096 | B1 4096] halfs = 64 KB
  __shared__ __align__(16) ushort lds[2*16384];

  const int tid  = threadIdx.x;
  const int wave = tid >> 6;
  const int lane = tid & 63;
  const int l15  = lane & 15;
  const int quad = lane >> 4;
  const int wm   = wave & 1;    // M half (64 rows)
  const int wn   = wave >> 1;   // j half (16 cols of each gate)

  // XCD partition: xcd x owns mb in {(x&1)*8 + 0..7}, nb in {(x>>1)*8 + 0..7}
  // -> per-XCD L2 working set = A 2MB + W 2MB (R4-proven: FETCH stays ideal).
  const int bid = blockIdx.x;
  const int xcd = bid & 7, u = bid >> 3;
  const int mb  = ((xcd & 1) << 3) | (u & 7);       // 0..15
  const int nb  = ((xcd >> 1) << 3) | (u >> 3);     // 0..31
  const int n0  = nb << 5;

  f32x4 acc[4][4];   // [gate][mt]
  #pragma unroll
  for (int g = 0; g < 4; g++)
    #pragma unroll
    for (int mt = 0; mt < 4; mt++)
      acc[g][mt] = (f32x4){0.f, 0.f, 0.f, 0.f};

  const ushort* aB = hin + (size_t)mb*32*4096;
  const ushort* wB = wpk + (size_t)nb*32*4096;

  const int dOff = tid*8;   // halfs; 256 thr x 16B = 2048 halfs per instr

  // Stage one BK=64 double-tile: A (8KB) + B (8KB), both linear spans.
  #define DMA_TILE(kt2, buf) do {                                             \
    const ushort* s0 = aB + (size_t)(kt2)*8192;                               \
    const ushort* s1 = wB + (size_t)(kt2)*8192;                               \
    ushort* d = &lds[(buf)*16384];                                            \
    __builtin_amdgcn_global_load_lds((gas_p)(s0+dOff),      (las_p)(d+dOff),       16,0,0); \
    __builtin_amdgcn_global_load_lds((gas_p)(s0+2048+dOff), (las_p)(d+2048+dOff),  16,0,0); \
    __builtin_amdgcn_global_load_lds((gas_p)(s0+4096+dOff), (las_p)(d+4096+dOff),  16,0,0); \
    __builtin_amdgcn_global_load_lds((gas_p)(s0+6144+dOff), (las_p)(d+6144+dOff),  16,0,0); \
    __builtin_amdgcn_global_load_lds((gas_p)(s1+dOff),      (las_p)(d+8192+dOff),  16,0,0); \
    __builtin_amdgcn_global_load_lds((gas_p)(s1+2048+dOff), (las_p)(d+10240+dOff), 16,0,0); \
    __builtin_amdgcn_global_load_lds((gas_p)(s1+4096+dOff), (las_p)(d+12288+dOff), 16,0,0); \
    __builtin_amdgcn_global_load_lds((gas_p)(s1+6144+dOff), (las_p)(d+14336+dOff), 16,0,0); \
  } while (0)

  // kt-invariant swizzled frag-read offsets (halfs); kk half adds +4096.
  int offA[4], offB[4];
  #pragma unroll
  for (int mt = 0; mt < 4; mt++) {
    const int r = wm*64 + mt*16 + l15;             // 0..127
    offA[mt] = POFF(r, quad);
  }
  #pragma unroll
  for (int g = 0; g < 4; g++) {
    const int r = g*32 + wn*16 + l15;              // 0..127
    offB[g] = 8192 + POFF(r, quad);
  }

  DMA_TILE(0, 0);

  #pragma unroll 1
  for (int kt2 = 0; kt2 < HID/64; kt2++) {
    const int sb = (kt2 & 1) * 16384;
    __syncthreads();                       // drains vmcnt -> double-tile resident
    if (kt2 + 1 < HID/64) DMA_TILE(kt2 + 1, (kt2 + 1) & 1);  // flies during compute

    f16x8 a[2][4], b[2][4];
    #pragma unroll
    for (int kk = 0; kk < 2; kk++) {
      #pragma unroll
      for (int mt = 0; mt < 4; mt++)
        a[kk][mt] = *reinterpret_cast<const f16x8*>(&lds[sb + kk*4096 + offA[mt]]);
      #pragma unroll
      for (int g = 0; g < 4; g++)
        b[kk][g] = *reinterpret_cast<const f16x8*>(&lds[sb + kk*4096 + offB[g]]);
    }

    #pragma unroll
    for (int kk = 0; kk < 2; kk++)
      #pragma unroll
      for (int g = 0; g < 4; g++)
        #pragma unroll
        for (int mt = 0; mt < 4; mt++)
          acc[g][mt] = __builtin_amdgcn_mfma_f32_16x16x32_f16(a[kk][mt], b[kk][g], acc[g][mt], 0, 0, 0);
  }
  #undef DMA_TILE

  // Epilogue: fused LSTM cell. C/D layout: col = lane&15, row = quad*4 + reg.
  const int fl = *flag;
  const int j = n0 + wn*16 + l15;
  float bi[4], m0v[4], m1v[4];
  #pragma unroll
  for (int g = 0; g < 4; g++) {
    bi[g]  = Beff[g*HID + j];
    m0v[g] = M0[g*HID + j];
    m1v[g] = M1[g*HID + j];
  }
  const int jq = (j >> 3) & 3;   // k-chunk of col j in next step's packed h
  #pragma unroll
  for (int mt = 0; mt < 4; mt++) {
    #pragma unroll
    for (int r = 0; r < 4; r++) {
      const int bl7 = wm*64 + mt*16 + quad*4 + r;   // b & 127
      const int b   = mb*128 + bl7;
      const long oidx = ((long)t_step * B_SZ + b) * 2;
      const float o0 = rdv(obs_raw, oidx, fl);
      const float o1 = rdv(obs_raw, oidx + 1, fl);
      const size_t off = (size_t)b*HID + j;
      float pi = acc[0][mt][r] + o0*m0v[0] + o1*m1v[0] + bi[0];
      float pf = acc[1][mt][r] + o0*m0v[1] + o1*m1v[1] + bi[1];
      float pg = acc[2][mt][r] + o0*m0v[2] + o1*m1v[2] + bi[2];
      float po = acc[3][mt][r] + o0*m0v[3] + o1*m1v[3] + bi[3];
      float cn = sigm(pf)*c_state[off] + sigm(pi)*tanh_f(pg);
      float hn = sigm(po)*tanh_f(cn);
      c_state[off] = cn;
      if (is_final) {
        if (fl) ((float*)out_final)[off] = hn;
        else    ((ushort*)out_final)[off] = f2bf(hn);
      } else {
        const long hpo = ((long)mb*32 + (j >> 5))*4096 + POFF(bl7, jq) + (j & 7);
        hout[hpo] = f2h(hn);
      }
    }
  }
}

extern "C" void kernel_launch(void* const* d_in, const int* in_sizes, int n_in,
                              void* d_out, int out_size, void* d_ws, size_t ws_size,
                              hipStream_t stream) {
  const void* obs  = d_in[0];
  const void* h0   = d_in[1];
  const void* c0   = d_in[2];
  const void* Wemb = d_in[3];
  const void* bemb = d_in[4];
  const void* Wih  = d_in[5];
  const void* Whh  = d_in[6];
  const void* bih  = d_in[7];
  const void* bhh  = d_in[8];

  char* w = (char*)d_ws;
  int*    flag    = (int*)w;
  float*  M0      = (float*)(w + 256);
  float*  M1      = M0 + G4;
  float*  Beff    = M1 + G4;
  float*  c_state = Beff + G4;                              // 8 MB
  ushort* wpk     = (ushort*)(c_state + (size_t)B_SZ*HID);  // 8 MB packed W (fp16)
  ushort* hA      = wpk + (size_t)G4*HID;                   // 4 MB
  ushort* hB      = hA + (size_t)B_SZ*HID;                  // 4 MB  (~24 MB total)

  detect_dtype<<<1, 1, 0, stream>>>((const ushort*)h0, flag);

  long totalCanon = 2L*B_SZ*HID + (long)G4*HID;
  canon<<<(int)((totalCanon + 255)/256), 256, 0, stream>>>(
      h0, c0, Whh, flag, hA, c_state, wpk);

  fold_emb<<<G4, 64, 0, stream>>>(Wih, Wemb, bemb, bih, bhh, flag, M0, M1, Beff);

  for (int t = 0; t < T_LEN; t++) {
    const ushort* ih = (t & 1) ? hB : hA;
    ushort* oh = (t & 1) ? hA : hB;
    lstm_step<<<512, 256, 0, stream>>>(ih, oh, d_out, c_state,
                                       wpk, M0, M1, Beff,
                                       obs, t, flag, (t == T_LEN - 1) ? 1 : 0);
  }
}

// Round 9
// 681.300 us; speedup vs baseline: 1.0790x; 1.0157x over previous
//
#include <hip/hip_runtime.h>

#define B_SZ 2048
#define HID  1024
#define G4   4096
#define IN_D 512
#define T_LEN 20

// Tile swizzle: 16B chunk q of row r stored at q ^ ((r>>1)&3) -> b128 frag
// reads land 8 banks x 2-way (free, m136); DMA writes stay linear.
#define POFF(r, q) ((r)*32 + ((((q) ^ (((r) >> 1) & 3))) << 3))

typedef __attribute__((ext_vector_type(8))) _Float16 f16x8;
typedef __attribute__((ext_vector_type(4))) float f32x4;
typedef const __attribute__((address_space(1))) void* gas_p;
typedef __attribute__((address_space(3))) void* las_p;

__device__ __forceinline__ float bf2f(ushort u){
  union { unsigned int i; float f; } v; v.i = ((unsigned int)u) << 16; return v.f;
}
__device__ __forceinline__ ushort f2bf(float f){
  union { float f; unsigned int i; } v; v.f = f;
  unsigned int r = v.i + 0x7fffu + ((v.i >> 16) & 1u);
  return (ushort)(r >> 16);
}
// fp16 RTN. All tensor magnitudes here (|h|<=1, |W|~0.03, |c0|~N(0,1)) are far
// inside fp16 range; rel err 2^-11 beats bf16's 2^-9.
__device__ __forceinline__ ushort f2h(float f){
  _Float16 h = (_Float16)f;
  union { _Float16 h; ushort u; } v; v.h = h; return v.u;
}
__device__ __forceinline__ float rdv(const void* p, long idx, int fl){
  return fl ? ((const float*)p)[idx] : bf2f(((const ushort*)p)[idx]);
}
__device__ __forceinline__ float sigm(float x){ return 1.0f/(1.0f + __expf(-x)); }
__device__ __forceinline__ float tanh_f(float x){
  float e = __expf(2.0f*x);
  return 1.0f - 2.0f/(e + 1.0f);
}

// flag=1 -> fp32 inputs; flag=0 -> bf16.
__global__ void detect_dtype(const ushort* __restrict__ h0bits, int* __restrict__ flag){
  int weird = 0;
  for (int i = 0; i < 256; i += 2){
    float a = fabsf(bf2f(h0bits[i]));
    if (!(a >= 1e-8f && a <= 1e4f)) weird++;
  }
  *flag = (weird >= 32) ? 1 : 0;
}

// Packed+swizzled fp16 layouts (every wave-level access = dense span):
//   h: tile (mb*32+kt) of 4096 halfs, element (b&127, j&31) at POFF
//   W: tile (nb*32+kt) of 4096 halfs, row r = g*32+(j&31)
__global__ void canon(const void* __restrict__ h0, const void* __restrict__ c0,
                      const void* __restrict__ whh, const int* __restrict__ flag,
                      ushort* __restrict__ hA,
                      float* __restrict__ c_state,
                      ushort* __restrict__ wpk){
  const int fl = *flag;
  long i = (long)blockIdx.x * 256 + threadIdx.x;
  const long N1 = (long)B_SZ * HID;
  const long N3 = (long)G4 * HID;
  if (i < N1){
    const int b = (int)(i >> 10), j = (int)(i & 1023);
    const int r = b & 127, q = (j >> 3) & 3;
    const long po = ((long)(b >> 7)*32 + (j >> 5))*4096 + POFF(r, q) + (j & 7);
    hA[po] = f2h(rdv(h0, i, fl));
    return;
  }
  i -= N1;
  if (i < N1){ c_state[i] = rdv(c0, i, fl); return; }
  i -= N1;
  if (i < N3){
    const int n = (int)(i >> 10), k = (int)(i & 1023);
    const int g = n >> 10, j = n & 1023;
    const int nb = j >> 5, r = g*32 + (j & 31);
    const int kt = k >> 5, q = (k >> 3) & 3;
    const long base = ((long)(nb*32 + kt))*4096 + POFF(r, q) + (k & 7);
    wpk[base] = f2h(rdv(whh, i, fl));
  }
}

// Fold embedding + input GEMM + biases into exact rank-2 update:
// gates_x[t,b,n] = obs[t,b,0]*M0[n] + obs[t,b,1]*M1[n] + Beff[n]
__global__ void fold_emb(const void* __restrict__ Wih, const void* __restrict__ Wemb,
                         const void* __restrict__ bemb, const void* __restrict__ bih,
                         const void* __restrict__ bhh, const int* __restrict__ flag,
                         float* __restrict__ M0, float* __restrict__ M1, float* __restrict__ Beff){
  const int n = blockIdx.x;
  const int lane = threadIdx.x;
  const int fl = *flag;
  float s0 = 0.f, s1 = 0.f, sb = 0.f;
  for (int j = lane; j < IN_D; j += 64){
    float w  = rdv(Wih, (long)n*IN_D + j, fl);
    float e0 = rdv(Wemb, 2L*j, fl);
    float e1 = rdv(Wemb, 2L*j + 1, fl);
    float be = rdv(bemb, j, fl);
    s0 += w*e0; s1 += w*e1; sb += w*be;
  }
  #pragma unroll
  for (int off = 32; off > 0; off >>= 1){
    s0 += __shfl_down(s0, off, 64);
    s1 += __shfl_down(s1, off, 64);
    sb += __shfl_down(sb, off, 64);
  }
  if (lane == 0){
    M0[n] = s0; M1[n] = s1;
    Beff[n] = sb + rdv(bih, n, fl) + rdv(bhh, n, fl);
  }
}

// R4 (654us, best) + two additive changes:
// (1) c_state/obs epilogue operands prefetched BEFORE the K-loop -- their
//     HBM/L2 latency hides under 32 iters of compute instead of landing as a
//     serial per-block tail (c_state cycles through HBM every step: the 8 MB
//     c-term in FETCH_SIZE). Same loads, same values -> bit-identical output.
// (2) s_setprio(1) around the MFMA cluster (T5): 2 independently-phased
//     blocks/CU = genuine role diversity for the CU scheduler to arbitrate.
__global__ __launch_bounds__(256, 2)
void lstm_step(const ushort* __restrict__ hin, ushort* __restrict__ hout,
               void* __restrict__ out_final,
               float* __restrict__ c_state,
               const ushort* __restrict__ wpk,
               const float* __restrict__ M0, const float* __restrict__ M1,
               const float* __restrict__ Beff,
               const void* __restrict__ obs_raw, int t_step,
               const int* __restrict__ flag, int is_final)
{
  // [buf][A 4096 | B 4096] halfs = 32 KB
  __shared__ __align__(16) ushort lds[2*8192];

  const int tid  = threadIdx.x;
  const int wave = tid >> 6;
  const int lane = tid & 63;
  const int l15  = lane & 15;
  const int quad = lane >> 4;
  const int wm   = wave & 1;    // M half (64 rows)
  const int wn   = wave >> 1;   // j half (16 cols of each gate)

  // XCD partition: xcd x owns mb in {(x&1)*8 + 0..7}, nb in {(x>>1)*8 + 0..7}
  const int bid = blockIdx.x;
  const int xcd = bid & 7, u = bid >> 3;
  const int mb  = ((xcd & 1) << 3) | (u & 7);       // 0..15
  const int nb  = ((xcd >> 1) << 3) | (u >> 3);     // 0..31
  const int n0  = nb << 5;

  f32x4 acc[4][4];   // [gate][mt]
  #pragma unroll
  for (int g = 0; g < 4; g++)
    #pragma unroll
    for (int mt = 0; mt < 4; mt++)
      acc[g][mt] = (f32x4){0.f, 0.f, 0.f, 0.f};

  const ushort* aB = hin + (size_t)mb*32*4096;
  const ushort* wB = wpk + (size_t)nb*32*4096;

  const int dOff = tid*8;   // halfs; 256 thr x 16B = 4KB per instr

  #define DMA_TILE(kt, buf) do {                                              \
    const ushort* s0 = aB + (size_t)(kt)*4096;                                \
    const ushort* s1 = wB + (size_t)(kt)*4096;                                \
    ushort* d = &lds[(buf)*8192];                                             \
    __builtin_amdgcn_global_load_lds((gas_p)(s0+dOff),      (las_p)(d+dOff),      16,0,0); \
    __builtin_amdgcn_global_load_lds((gas_p)(s0+2048+dOff), (las_p)(d+2048+dOff), 16,0,0); \
    __builtin_amdgcn_global_load_lds((gas_p)(s1+dOff),      (las_p)(d+4096+dOff), 16,0,0); \
    __builtin_amdgcn_global_load_lds((gas_p)(s1+2048+dOff), (las_p)(d+6144+dOff), 16,0,0); \
  } while (0)

  // kt-invariant swizzled frag-read offsets (halfs)
  int offA[4], offB[4];
  #pragma unroll
  for (int mt = 0; mt < 4; mt++) {
    const int r = wm*64 + mt*16 + l15;             // 0..127
    offA[mt] = POFF(r, quad);
  }
  #pragma unroll
  for (int g = 0; g < 4; g++) {
    const int r = g*32 + wn*16 + l15;              // 0..127
    offB[g] = 4096 + POFF(r, quad);
  }

  // ---- Epilogue-operand prefetch (issues at kernel start; completes under
  // the K-loop; first __syncthreads drains them once, then never again).
  const int fl = *flag;
  const int j = n0 + wn*16 + l15;
  float cpre[4][4], o0p[4][4], o1p[4][4];
  #pragma unroll
  for (int mt = 0; mt < 4; mt++)
    #pragma unroll
    for (int r = 0; r < 4; r++) {
      const int bl7 = wm*64 + mt*16 + quad*4 + r;   // b & 127
      const int b   = mb*128 + bl7;
      cpre[mt][r] = c_state[(size_t)b*HID + j];
      const long oidx = ((long)t_step * B_SZ + b) * 2;
      o0p[mt][r] = rdv(obs_raw, oidx, fl);
      o1p[mt][r] = rdv(obs_raw, oidx + 1, fl);
    }

  DMA_TILE(0, 0);

  #pragma unroll 1
  for (int kt = 0; kt < HID/32; kt++) {
    const int sb = (kt & 1) * 8192;
    __syncthreads();                       // drains vmcnt -> tile kt resident
    if (kt + 1 < HID/32) DMA_TILE(kt + 1, (kt + 1) & 1);   // flies during compute

    f16x8 a[4], b[4];
    #pragma unroll
    for (int mt = 0; mt < 4; mt++)
      a[mt] = *reinterpret_cast<const f16x8*>(&lds[sb + offA[mt]]);
    #pragma unroll
    for (int g = 0; g < 4; g++)
      b[g] = *reinterpret_cast<const f16x8*>(&lds[sb + offB[g]]);

    __builtin_amdgcn_s_setprio(1);
    #pragma unroll
    for (int g = 0; g < 4; g++)
      #pragma unroll
      for (int mt = 0; mt < 4; mt++)
        acc[g][mt] = __builtin_amdgcn_mfma_f32_16x16x32_f16(a[mt], b[g], acc[g][mt], 0, 0, 0);
    __builtin_amdgcn_s_setprio(0);
  }
  #undef DMA_TILE

  // Epilogue: fused LSTM cell. C/D layout: col = lane&15, row = quad*4 + reg.
  float bi[4], m0v[4], m1v[4];
  #pragma unroll
  for (int g = 0; g < 4; g++) {
    bi[g]  = Beff[g*HID + j];
    m0v[g] = M0[g*HID + j];
    m1v[g] = M1[g*HID + j];
  }
  const int jq = (j >> 3) & 3;   // k-chunk of col j in next step's packed h
  #pragma unroll
  for (int mt = 0; mt < 4; mt++) {
    #pragma unroll
    for (int r = 0; r < 4; r++) {
      const int bl7 = wm*64 + mt*16 + quad*4 + r;   // b & 127
      const int b   = mb*128 + bl7;
      const float o0 = o0p[mt][r];
      const float o1 = o1p[mt][r];
      const size_t off = (size_t)b*HID + j;
      float pi = acc[0][mt][r] + o0*m0v[0] + o1*m1v[0] + bi[0];
      float pf = acc[1][mt][r] + o0*m0v[1] + o1*m1v[1] + bi[1];
      float pg = acc[2][mt][r] + o0*m0v[2] + o1*m1v[2] + bi[2];
      float po = acc[3][mt][r] + o0*m0v[3] + o1*m1v[3] + bi[3];
      float cn = sigm(pf)*cpre[mt][r] + sigm(pi)*tanh_f(pg);
      float hn = sigm(po)*tanh_f(cn);
      c_state[off] = cn;
      if (is_final) {
        if (fl) ((float*)out_final)[off] = hn;
        else    ((ushort*)out_final)[off] = f2bf(hn);
      } else {
        const long hpo = ((long)mb*32 + (j >> 5))*4096 + POFF(bl7, jq) + (j & 7);
        hout[hpo] = f2h(hn);
      }
    }
  }
}

extern "C" void kernel_launch(void* const* d_in, const int* in_sizes, int n_in,
                              void* d_out, int out_size, void* d_ws, size_t ws_size,
                              hipStream_t stream) {
  const void* obs  = d_in[0];
  const void* h0   = d_in[1];
  const void* c0   = d_in[2];
  const void* Wemb = d_in[3];
  const void* bemb = d_in[4];
  const void* Wih  = d_in[5];
  const void* Whh  = d_in[6];
  const void* bih  = d_in[7];
  const void* bhh  = d_in[8];

  char* w = (char*)d_ws;
  int*    flag    = (int*)w;
  float*  M0      = (float*)(w + 256);
  float*  M1      = M0 + G4;
  float*  Beff    = M1 + G4;
  float*  c_state = Beff + G4;                              // 8 MB
  ushort* wpk     = (ushort*)(c_state + (size_t)B_SZ*HID);  // 8 MB packed W (fp16)
  ushort* hA      = wpk + (size_t)G4*HID;                   // 4 MB
  ushort* hB      = hA + (size_t)B_SZ*HID;                  // 4 MB  (~24 MB total)

  detect_dtype<<<1, 1, 0, stream>>>((const ushort*)h0, flag);

  long totalCanon = 2L*B_SZ*HID + (long)G4*HID;
  canon<<<(int)((totalCanon + 255)/256), 256, 0, stream>>>(
      h0, c0, Whh, flag, hA, c_state, wpk);

  fold_emb<<<G4, 64, 0, stream>>>(Wih, Wemb, bemb, bih, bhh, flag, M0, M1, Beff);

  for (int t = 0; t < T_LEN; t++) {
    const ushort* ih = (t & 1) ? hB : hA;
    ushort* oh = (t & 1) ? hA : hB;
    lstm_step<<<512, 256, 0, stream>>>(ih, oh, d_out, c_state,
                                       wpk, M0, M1, Beff,
                                       obs, t, flag, (t == T_LEN - 1) ? 1 : 0);
  }
}

// Round 10
// 648.959 us; speedup vs baseline: 1.1328x; 1.0498x over previous
//
#include <hip/hip_runtime.h>

#define B_SZ 2048
#define HID  1024
#define G4   4096
#define IN_D 512
#define T_LEN 20

// Tile swizzle: 16B chunk q of row r stored at q ^ ((r>>1)&3) -> b128 frag
// reads land 8 banks x 2-way (free, m136); DMA writes stay linear.
#define POFF(r, q) ((r)*32 + ((((q) ^ (((r) >> 1) & 3))) << 3))

typedef __attribute__((ext_vector_type(8))) _Float16 f16x8;
typedef __attribute__((ext_vector_type(4))) float f32x4;
typedef const __attribute__((address_space(1))) void* gas_p;
typedef __attribute__((address_space(3))) void* las_p;

__device__ __forceinline__ float bf2f(ushort u){
  union { unsigned int i; float f; } v; v.i = ((unsigned int)u) << 16; return v.f;
}
__device__ __forceinline__ ushort f2bf(float f){
  union { float f; unsigned int i; } v; v.f = f;
  unsigned int r = v.i + 0x7fffu + ((v.i >> 16) & 1u);
  return (ushort)(r >> 16);
}
// fp16 RTN. All tensor magnitudes here (|h|<=1, |W|~0.03, |c0|~N(0,1)) are far
// inside fp16 range; rel err 2^-11 beats bf16's 2^-9.
__device__ __forceinline__ ushort f2h(float f){
  _Float16 h = (_Float16)f;
  union { _Float16 h; ushort u; } v; v.h = h; return v.u;
}
__device__ __forceinline__ float rdv(const void* p, long idx, int fl){
  return fl ? ((const float*)p)[idx] : bf2f(((const ushort*)p)[idx]);
}
__device__ __forceinline__ float sigm(float x){ return 1.0f/(1.0f + __expf(-x)); }
__device__ __forceinline__ float tanh_f(float x){
  float e = __expf(2.0f*x);
  return 1.0f - 2.0f/(e + 1.0f);
}

// flag=1 -> fp32 inputs; flag=0 -> bf16.
__global__ void detect_dtype(const ushort* __restrict__ h0bits, int* __restrict__ flag){
  int weird = 0;
  for (int i = 0; i < 256; i += 2){
    float a = fabsf(bf2f(h0bits[i]));
    if (!(a >= 1e-8f && a <= 1e4f)) weird++;
  }
  *flag = (weird >= 32) ? 1 : 0;
}

// Packed+swizzled fp16 layouts (every wave-level access = dense span):
//   h: tile (mb*32+kt) of 4096 halfs, element (b&127, j&31) at POFF
//   W: tile (nb*32+kt) of 4096 halfs, row r = g*32+(j&31)
__global__ void canon(const void* __restrict__ h0, const void* __restrict__ c0,
                      const void* __restrict__ whh, const int* __restrict__ flag,
                      ushort* __restrict__ hA,
                      float* __restrict__ c_state,
                      ushort* __restrict__ wpk){
  const int fl = *flag;
  long i = (long)blockIdx.x * 256 + threadIdx.x;
  const long N1 = (long)B_SZ * HID;
  const long N3 = (long)G4 * HID;
  if (i < N1){
    const int b = (int)(i >> 10), j = (int)(i & 1023);
    const int r = b & 127, q = (j >> 3) & 3;
    const long po = ((long)(b >> 7)*32 + (j >> 5))*4096 + POFF(r, q) + (j & 7);
    hA[po] = f2h(rdv(h0, i, fl));
    return;
  }
  i -= N1;
  if (i < N1){ c_state[i] = rdv(c0, i, fl); return; }
  i -= N1;
  if (i < N3){
    const int n = (int)(i >> 10), k = (int)(i & 1023);
    const int g = n >> 10, j = n & 1023;
    const int nb = j >> 5, r = g*32 + (j & 31);
    const int kt = k >> 5, q = (k >> 3) & 3;
    const long base = ((long)(nb*32 + kt))*4096 + POFF(r, q) + (k & 7);
    wpk[base] = f2h(rdv(whh, i, fl));
  }
}

// Fold embedding + input GEMM + biases into exact rank-2 update:
// gates_x[t,b,n] = obs[t,b,0]*M0[n] + obs[t,b,1]*M1[n] + Beff[n]
__global__ void fold_emb(const void* __restrict__ Wih, const void* __restrict__ Wemb,
                         const void* __restrict__ bemb, const void* __restrict__ bih,
                         const void* __restrict__ bhh, const int* __restrict__ flag,
                         float* __restrict__ M0, float* __restrict__ M1, float* __restrict__ Beff){
  const int n = blockIdx.x;
  const int lane = threadIdx.x;
  const int fl = *flag;
  float s0 = 0.f, s1 = 0.f, sb = 0.f;
  for (int j = lane; j < IN_D; j += 64){
    float w  = rdv(Wih, (long)n*IN_D + j, fl);
    float e0 = rdv(Wemb, 2L*j, fl);
    float e1 = rdv(Wemb, 2L*j + 1, fl);
    float be = rdv(bemb, j, fl);
    s0 += w*e0; s1 += w*e1; sb += w*be;
  }
  #pragma unroll
  for (int off = 32; off > 0; off >>= 1){
    s0 += __shfl_down(s0, off, 64);
    s1 += __shfl_down(s1, off, 64);
    sb += __shfl_down(sb, off, 64);
  }
  if (lane == 0){
    M0[n] = s0; M1[n] = s1;
    Beff[n] = sb + rdv(bih, n, fl) + rdv(bhh, n, fl);
  }
}

// fp16 single-term GEMM in the R0-proven HIGH-OCCUPANCY geometry:
// 512 thr / 8 waves (wm 4 x wn 2, wave-tile 32x64, acc[4][2]), tile 128x128,
// grid 512 = 2 blocks/CU = 16 waves/CU = 4 waves/SIMD. R0 measured 17 cyc/KB
// of LDS traffic at this occupancy vs 25 cyc/KB for R4's 2 waves/SIMD — the
// ds_read->MFMA chain hides behind 3 other waves per SIMD. Single-barrier
// dbuf loop (proven), 2 DMA instr/iter (512thr x 16B = 8KB per instr).
// Numerics identical to R4 -> bit-identical output.
__global__ __launch_bounds__(512, 4)
void lstm_step(const ushort* __restrict__ hin, ushort* __restrict__ hout,
               void* __restrict__ out_final,
               float* __restrict__ c_state,
               const ushort* __restrict__ wpk,
               const float* __restrict__ M0, const float* __restrict__ M1,
               const float* __restrict__ Beff,
               const void* __restrict__ obs_raw, int t_step,
               const int* __restrict__ flag, int is_final)
{
  // [buf][A 4096 | B 4096] halfs = 32 KB
  __shared__ __align__(16) ushort lds[2*8192];

  const int tid  = threadIdx.x;
  const int wave = tid >> 6;
  const int lane = tid & 63;
  const int l15  = lane & 15;
  const int quad = lane >> 4;
  const int wm   = wave & 3;    // M quarter (32 rows)
  const int wn   = wave >> 2;   // j half (16 cols of each gate)

  // XCD partition: xcd x owns mb in {(x&1)*8 + 0..7}, nb in {(x>>1)*8 + 0..7}
  // -> per-XCD L2 working set = A 2MB + W 2MB (R4-proven: FETCH stays ideal).
  const int bid = blockIdx.x;
  const int xcd = bid & 7, u = bid >> 3;
  const int mb  = ((xcd & 1) << 3) | (u & 7);       // 0..15
  const int nb  = ((xcd >> 1) << 3) | (u >> 3);     // 0..31
  const int n0  = nb << 5;

  f32x4 acc[4][2];   // [gate][mt]
  #pragma unroll
  for (int g = 0; g < 4; g++)
    #pragma unroll
    for (int mt = 0; mt < 2; mt++)
      acc[g][mt] = (f32x4){0.f, 0.f, 0.f, 0.f};

  const ushort* aB = hin + (size_t)mb*32*4096;
  const ushort* wB = wpk + (size_t)nb*32*4096;

  const int dOff = tid*8;   // halfs; 512 thr x 16B = full 8KB tile per instr

  #define DMA_TILE(kt, buf) do {                                              \
    const ushort* s0 = aB + (size_t)(kt)*4096;                                \
    const ushort* s1 = wB + (size_t)(kt)*4096;                                \
    ushort* d = &lds[(buf)*8192];                                             \
    __builtin_amdgcn_global_load_lds((gas_p)(s0+dOff), (las_p)(d+dOff),      16,0,0); \
    __builtin_amdgcn_global_load_lds((gas_p)(s1+dOff), (las_p)(d+4096+dOff), 16,0,0); \
  } while (0)

  // kt-invariant swizzled frag-read offsets (halfs)
  int offA[2], offB[4];
  #pragma unroll
  for (int mt = 0; mt < 2; mt++) {
    const int r = wm*32 + mt*16 + l15;             // 0..127
    offA[mt] = POFF(r, quad);
  }
  #pragma unroll
  for (int g = 0; g < 4; g++) {
    const int r = g*32 + wn*16 + l15;              // 0..127
    offB[g] = 4096 + POFF(r, quad);
  }

  DMA_TILE(0, 0);

  #pragma unroll 1
  for (int kt = 0; kt < HID/32; kt++) {
    const int sb = (kt & 1) * 8192;
    __syncthreads();                       // drains vmcnt -> tile kt resident
    if (kt + 1 < HID/32) DMA_TILE(kt + 1, (kt + 1) & 1);   // flies during compute

    f16x8 a[2], b[4];
    #pragma unroll
    for (int mt = 0; mt < 2; mt++)
      a[mt] = *reinterpret_cast<const f16x8*>(&lds[sb + offA[mt]]);
    #pragma unroll
    for (int g = 0; g < 4; g++)
      b[g] = *reinterpret_cast<const f16x8*>(&lds[sb + offB[g]]);

    #pragma unroll
    for (int g = 0; g < 4; g++) {
      acc[g][0] = __builtin_amdgcn_mfma_f32_16x16x32_f16(a[0], b[g], acc[g][0], 0, 0, 0);
      acc[g][1] = __builtin_amdgcn_mfma_f32_16x16x32_f16(a[1], b[g], acc[g][1], 0, 0, 0);
    }
  }
  #undef DMA_TILE

  // Epilogue: fused LSTM cell. C/D layout: col = lane&15, row = quad*4 + reg.
  const int fl = *flag;
  const int j = n0 + wn*16 + l15;
  float bi[4], m0v[4], m1v[4];
  #pragma unroll
  for (int g = 0; g < 4; g++) {
    bi[g]  = Beff[g*HID + j];
    m0v[g] = M0[g*HID + j];
    m1v[g] = M1[g*HID + j];
  }
  const int jq = (j >> 3) & 3;   // k-chunk of col j in next step's packed h
  #pragma unroll
  for (int mt = 0; mt < 2; mt++) {
    #pragma unroll
    for (int r = 0; r < 4; r++) {
      const int bl7 = wm*32 + mt*16 + quad*4 + r;   // b & 127
      const int b   = mb*128 + bl7;
      const long oidx = ((long)t_step * B_SZ + b) * 2;
      const float o0 = rdv(obs_raw, oidx, fl);
      const float o1 = rdv(obs_raw, oidx + 1, fl);
      const size_t off = (size_t)b*HID + j;
      float pi = acc[0][mt][r] + o0*m0v[0] + o1*m1v[0] + bi[0];
      float pf = acc[1][mt][r] + o0*m0v[1] + o1*m1v[1] + bi[1];
      float pg = acc[2][mt][r] + o0*m0v[2] + o1*m1v[2] + bi[2];
      float po = acc[3][mt][r] + o0*m0v[3] + o1*m1v[3] + bi[3];
      float cn = sigm(pf)*c_state[off] + sigm(pi)*tanh_f(pg);
      float hn = sigm(po)*tanh_f(cn);
      c_state[off] = cn;
      if (is_final) {
        if (fl) ((float*)out_final)[off] = hn;
        else    ((ushort*)out_final)[off] = f2bf(hn);
      } else {
        const long hpo = ((long)mb*32 + (j >> 5))*4096 + POFF(bl7, jq) + (j & 7);
        hout[hpo] = f2h(hn);
      }
    }
  }
}

extern "C" void kernel_launch(void* const* d_in, const int* in_sizes, int n_in,
                              void* d_out, int out_size, void* d_ws, size_t ws_size,
                              hipStream_t stream) {
  const void* obs  = d_in[0];
  const void* h0   = d_in[1];
  const void* c0   = d_in[2];
  const void* Wemb = d_in[3];
  const void* bemb = d_in[4];
  const void* Wih  = d_in[5];
  const void* Whh  = d_in[6];
  const void* bih  = d_in[7];
  const void* bhh  = d_in[8];

  char* w = (char*)d_ws;
  int*    flag    = (int*)w;
  float*  M0      = (float*)(w + 256);
  float*  M1      = M0 + G4;
  float*  Beff    = M1 + G4;
  float*  c_state = Beff + G4;                              // 8 MB
  ushort* wpk     = (ushort*)(c_state + (size_t)B_SZ*HID);  // 8 MB packed W (fp16)
  ushort* hA      = wpk + (size_t)G4*HID;                   // 4 MB
  ushort* hB      = hA + (size_t)B_SZ*HID;                  // 4 MB  (~24 MB total)

  detect_dtype<<<1, 1, 0, stream>>>((const ushort*)h0, flag);

  long totalCanon = 2L*B_SZ*HID + (long)G4*HID;
  canon<<<(int)((totalCanon + 255)/256), 256, 0, stream>>>(
      h0, c0, Whh, flag, hA, c_state, wpk);

  fold_emb<<<G4, 64, 0, stream>>>(Wih, Wemb, bemb, bih, bhh, flag, M0, M1, Beff);

  for (int t = 0; t < T_LEN; t++) {
    const ushort* ih = (t & 1) ? hB : hA;
    ushort* oh = (t & 1) ? hA : hB;
    lstm_step<<<512, 512, 0, stream>>>(ih, oh, d_out, c_state,
                                       wpk, M0, M1, Beff,
                                       obs, t, flag, (t == T_LEN - 1) ? 1 : 0);
  }
}

// Round 11
// 635.217 us; speedup vs baseline: 1.1573x; 1.0216x over previous
//
#include <hip/hip_runtime.h>

#define B_SZ 2048
#define HID  1024
#define G4   4096
#define IN_D 512
#define T_LEN 20
#define NT   (HID/32)

// Tile swizzle: 16B chunk q of row r stored at q ^ ((r>>1)&3) -> b128 frag
// reads land 8 banks x 2-way (free, m136); DMA writes stay linear.
#define POFF(r, q) ((r)*32 + ((((q) ^ (((r) >> 1) & 3))) << 3))

typedef __attribute__((ext_vector_type(8))) _Float16 f16x8;
typedef __attribute__((ext_vector_type(4))) float f32x4;
typedef const __attribute__((address_space(1))) void* gas_p;
typedef __attribute__((address_space(3))) void* las_p;

__device__ __forceinline__ float bf2f(ushort u){
  union { unsigned int i; float f; } v; v.i = ((unsigned int)u) << 16; return v.f;
}
__device__ __forceinline__ ushort f2bf(float f){
  union { float f; unsigned int i; } v; v.f = f;
  unsigned int r = v.i + 0x7fffu + ((v.i >> 16) & 1u);
  return (ushort)(r >> 16);
}
// fp16 RTN. All tensor magnitudes here (|h|<=1, |W|~0.03, |c0|~N(0,1)) are far
// inside fp16 range; rel err 2^-11 beats bf16's 2^-9.
__device__ __forceinline__ ushort f2h(float f){
  _Float16 h = (_Float16)f;
  union { _Float16 h; ushort u; } v; v.h = h; return v.u;
}
__device__ __forceinline__ float rdv(const void* p, long idx, int fl){
  return fl ? ((const float*)p)[idx] : bf2f(((const ushort*)p)[idx]);
}
__device__ __forceinline__ float sigm(float x){ return 1.0f/(1.0f + __expf(-x)); }
__device__ __forceinline__ float tanh_f(float x){
  float e = __expf(2.0f*x);
  return 1.0f - 2.0f/(e + 1.0f);
}

// flag=1 -> fp32 inputs; flag=0 -> bf16.
__global__ void detect_dtype(const ushort* __restrict__ h0bits, int* __restrict__ flag){
  int weird = 0;
  for (int i = 0; i < 256; i += 2){
    float a = fabsf(bf2f(h0bits[i]));
    if (!(a >= 1e-8f && a <= 1e4f)) weird++;
  }
  *flag = (weird >= 32) ? 1 : 0;
}

// Packed+swizzled fp16 layouts (every wave-level access = dense span):
//   h: tile (mb*32+kt) of 4096 halfs, element (b&127, j&31) at POFF
//   W: tile (nb*32+kt) of 4096 halfs, row r = g*32+(j&31)
__global__ void canon(const void* __restrict__ h0, const void* __restrict__ c0,
                      const void* __restrict__ whh, const int* __restrict__ flag,
                      ushort* __restrict__ hA,
                      float* __restrict__ c_state,
                      ushort* __restrict__ wpk){
  const int fl = *flag;
  long i = (long)blockIdx.x * 256 + threadIdx.x;
  const long N1 = (long)B_SZ * HID;
  const long N3 = (long)G4 * HID;
  if (i < N1){
    const int b = (int)(i >> 10), j = (int)(i & 1023);
    const int r = b & 127, q = (j >> 3) & 3;
    const long po = ((long)(b >> 7)*32 + (j >> 5))*4096 + POFF(r, q) + (j & 7);
    hA[po] = f2h(rdv(h0, i, fl));
    return;
  }
  i -= N1;
  if (i < N1){ c_state[i] = rdv(c0, i, fl); return; }
  i -= N1;
  if (i < N3){
    const int n = (int)(i >> 10), k = (int)(i & 1023);
    const int g = n >> 10, j = n & 1023;
    const int nb = j >> 5, r = g*32 + (j & 31);
    const int kt = k >> 5, q = (k >> 3) & 3;
    const long base = ((long)(nb*32 + kt))*4096 + POFF(r, q) + (k & 7);
    wpk[base] = f2h(rdv(whh, i, fl));
  }
}

// Fold embedding + input GEMM + biases into exact rank-2 update:
// gates_x[t,b,n] = obs[t,b,0]*M0[n] + obs[t,b,1]*M1[n] + Beff[n]
__global__ void fold_emb(const void* __restrict__ Wih, const void* __restrict__ Wemb,
                         const void* __restrict__ bemb, const void* __restrict__ bih,
                         const void* __restrict__ bhh, const int* __restrict__ flag,
                         float* __restrict__ M0, float* __restrict__ M1, float* __restrict__ Beff){
  const int n = blockIdx.x;
  const int lane = threadIdx.x;
  const int fl = *flag;
  float s0 = 0.f, s1 = 0.f, sb = 0.f;
  for (int j = lane; j < IN_D; j += 64){
    float w  = rdv(Wih, (long)n*IN_D + j, fl);
    float e0 = rdv(Wemb, 2L*j, fl);
    float e1 = rdv(Wemb, 2L*j + 1, fl);
    float be = rdv(bemb, j, fl);
    s0 += w*e0; s1 += w*e1; sb += w*be;
  }
  #pragma unroll
  for (int off = 32; off > 0; off >>= 1){
    s0 += __shfl_down(s0, off, 64);
    s1 += __shfl_down(s1, off, 64);
    sb += __shfl_down(sb, off, 64);
  }
  if (lane == 0){
    M0[n] = s0; M1[n] = s1;
    Beff[n] = sb + rdv(bih, n, fl) + rdv(bhh, n, fl);
  }
}

// R10 geometry (649us) with the full-drain dbuf loop replaced by a 3-buffer
// ring + depth-2 prefetch + counted vmcnt (T4). R4 vs R10 isolated the wall:
// same 2400cyc/iter at 33% different LDS traffic and 2x different occupancy
// -> per-iter latency chain, dominated by the __syncthreads vmcnt(0) drain
// that re-exposes DMA L2 latency every iteration. Here the barrier waits only
// vmcnt(2) (= the NEXT tile's own 2 loads); the tile-after-next's loads stay
// in flight ACROSS the barrier — never a full drain in the main loop.
// Ring safety ledger: buf being DMA'd (t+2 = t-1 mod 3) was last read before
// iter t-1's barrier (reads feed MFMA which precede that barrier); buf read
// at iter t+1 is fenced by each wave's own vmcnt(2) + s_barrier. Tail iters
// (no new DMA) wait vmcnt(0). Numerics/layout/epilogue identical to R10.
__global__ __launch_bounds__(512, 4)
void lstm_step(const ushort* __restrict__ hin, ushort* __restrict__ hout,
               void* __restrict__ out_final,
               float* __restrict__ c_state,
               const ushort* __restrict__ wpk,
               const float* __restrict__ M0, const float* __restrict__ M1,
               const float* __restrict__ Beff,
               const void* __restrict__ obs_raw, int t_step,
               const int* __restrict__ flag, int is_final)
{
  // 3-ring x [A 4096 | B 4096] halfs = 48 KB
  __shared__ __align__(16) ushort lds[3*8192];

  const int tid  = threadIdx.x;
  const int wave = tid >> 6;
  const int lane = tid & 63;
  const int l15  = lane & 15;
  const int quad = lane >> 4;
  const int wm   = wave & 3;    // M quarter (32 rows)
  const int wn   = wave >> 2;   // j half (16 cols of each gate)

  // XCD partition: xcd x owns mb in {(x&1)*8 + 0..7}, nb in {(x>>1)*8 + 0..7}
  // -> per-XCD L2 working set = A 2MB + W 2MB (R4-proven: FETCH stays ideal).
  const int bid = blockIdx.x;
  const int xcd = bid & 7, u = bid >> 3;
  const int mb  = ((xcd & 1) << 3) | (u & 7);       // 0..15
  const int nb  = ((xcd >> 1) << 3) | (u >> 3);     // 0..31
  const int n0  = nb << 5;

  f32x4 acc[4][2];   // [gate][mt]
  #pragma unroll
  for (int g = 0; g < 4; g++)
    #pragma unroll
    for (int mt = 0; mt < 2; mt++)
      acc[g][mt] = (f32x4){0.f, 0.f, 0.f, 0.f};

  const ushort* aB = hin + (size_t)mb*32*4096;
  const ushort* wB = wpk + (size_t)nb*32*4096;

  const int dOff = tid*8;   // halfs; 512 thr x 16B = full 8KB tile per instr

  // 2 vmcnt-counted instructions per tile stage (the vmcnt(2) math relies on this).
  #define DMA_TILE(kt, buf) do {                                              \
    const ushort* s0 = aB + (size_t)(kt)*4096;                                \
    const ushort* s1 = wB + (size_t)(kt)*4096;                                \
    ushort* d = &lds[(buf)*8192];                                             \
    __builtin_amdgcn_global_load_lds((gas_p)(s0+dOff), (las_p)(d+dOff),      16,0,0); \
    __builtin_amdgcn_global_load_lds((gas_p)(s1+dOff), (las_p)(d+4096+dOff), 16,0,0); \
  } while (0)

  // kt-invariant swizzled frag-read offsets (halfs)
  int offA[2], offB[4];
  #pragma unroll
  for (int mt = 0; mt < 2; mt++) {
    const int r = wm*32 + mt*16 + l15;             // 0..127
    offA[mt] = POFF(r, quad);
  }
  #pragma unroll
  for (int g = 0; g < 4; g++) {
    const int r = g*32 + wn*16 + l15;              // 0..127
    offB[g] = 4096 + POFF(r, quad);
  }

  // Prologue: stage tiles 0,1; wait only tile 0's loads (tile 1 stays in flight).
  DMA_TILE(0, 0);
  DMA_TILE(1, 1);
  asm volatile("s_waitcnt vmcnt(2)" ::: "memory");
  asm volatile("s_barrier" ::: "memory");

  int cur = 0;
  #pragma unroll 1
  for (int kt = 0; kt < NT; kt++) {
    const int sb = cur * 8192;

    f16x8 a[2], b[4];
    #pragma unroll
    for (int mt = 0; mt < 2; mt++)
      a[mt] = *reinterpret_cast<const f16x8*>(&lds[sb + offA[mt]]);
    #pragma unroll
    for (int g = 0; g < 4; g++)
      b[g] = *reinterpret_cast<const f16x8*>(&lds[sb + offB[g]]);

    // Issue tile kt+2 now: its L2 latency hides under the MFMAs below and the
    // next iteration's ds_reads; it is not needed until 2 barriers from now.
    if (kt + 2 < NT) {
      int stg = cur + 2; if (stg >= 3) stg -= 3;
      DMA_TILE(kt + 2, stg);
    }

    #pragma unroll
    for (int g = 0; g < 4; g++) {
      acc[g][0] = __builtin_amdgcn_mfma_f32_16x16x32_f16(a[0], b[g], acc[g][0], 0, 0, 0);
      acc[g][1] = __builtin_amdgcn_mfma_f32_16x16x32_f16(a[1], b[g], acc[g][1], 0, 0, 0);
    }

    // Counted wait: tile kt+1's 2 loads are the oldest outstanding; leave
    // kt+2's 2 in flight across the barrier (no full drain in main loop).
    if (kt + 2 < NT) asm volatile("s_waitcnt vmcnt(2)" ::: "memory");
    else             asm volatile("s_waitcnt vmcnt(0)" ::: "memory");
    asm volatile("s_barrier" ::: "memory");
    __builtin_amdgcn_sched_barrier(0);

    cur = (cur == 2) ? 0 : cur + 1;
  }
  #undef DMA_TILE

  // Epilogue: fused LSTM cell. C/D layout: col = lane&15, row = quad*4 + reg.
  const int fl = *flag;
  const int j = n0 + wn*16 + l15;
  float bi[4], m0v[4], m1v[4];
  #pragma unroll
  for (int g = 0; g < 4; g++) {
    bi[g]  = Beff[g*HID + j];
    m0v[g] = M0[g*HID + j];
    m1v[g] = M1[g*HID + j];
  }
  const int jq = (j >> 3) & 3;   // k-chunk of col j in next step's packed h
  #pragma unroll
  for (int mt = 0; mt < 2; mt++) {
    #pragma unroll
    for (int r = 0; r < 4; r++) {
      const int bl7 = wm*32 + mt*16 + quad*4 + r;   // b & 127
      const int b   = mb*128 + bl7;
      const long oidx = ((long)t_step * B_SZ + b) * 2;
      const float o0 = rdv(obs_raw, oidx, fl);
      const float o1 = rdv(obs_raw, oidx + 1, fl);
      const size_t off = (size_t)b*HID + j;
      float pi = acc[0][mt][r] + o0*m0v[0] + o1*m1v[0] + bi[0];
      float pf = acc[1][mt][r] + o0*m0v[1] + o1*m1v[1] + bi[1];
      float pg = acc[2][mt][r] + o0*m0v[2] + o1*m1v[2] + bi[2];
      float po = acc[3][mt][r] + o0*m0v[3] + o1*m1v[3] + bi[3];
      float cn = sigm(pf)*c_state[off] + sigm(pi)*tanh_f(pg);
      float hn = sigm(po)*tanh_f(cn);
      c_state[off] = cn;
      if (is_final) {
        if (fl) ((float*)out_final)[off] = hn;
        else    ((ushort*)out_final)[off] = f2bf(hn);
      } else {
        const long hpo = ((long)mb*32 + (j >> 5))*4096 + POFF(bl7, jq) + (j & 7);
        hout[hpo] = f2h(hn);
      }
    }
  }
}

extern "C" void kernel_launch(void* const* d_in, const int* in_sizes, int n_in,
                              void* d_out, int out_size, void* d_ws, size_t ws_size,
                              hipStream_t stream) {
  const void* obs  = d_in[0];
  const void* h0   = d_in[1];
  const void* c0   = d_in[2];
  const void* Wemb = d_in[3];
  const void* bemb = d_in[4];
  const void* Wih  = d_in[5];
  const void* Whh  = d_in[6];
  const void* bih  = d_in[7];
  const void* bhh  = d_in[8];

  char* w = (char*)d_ws;
  int*    flag    = (int*)w;
  float*  M0      = (float*)(w + 256);
  float*  M1      = M0 + G4;
  float*  Beff    = M1 + G4;
  float*  c_state = Beff + G4;                              // 8 MB
  ushort* wpk     = (ushort*)(c_state + (size_t)B_SZ*HID);  // 8 MB packed W (fp16)
  ushort* hA      = wpk + (size_t)G4*HID;                   // 4 MB
  ushort* hB      = hA + (size_t)B_SZ*HID;                  // 4 MB  (~24 MB total)

  detect_dtype<<<1, 1, 0, stream>>>((const ushort*)h0, flag);

  long totalCanon = 2L*B_SZ*HID + (long)G4*HID;
  canon<<<(int)((totalCanon + 255)/256), 256, 0, stream>>>(
      h0, c0, Whh, flag, hA, c_state, wpk);

  fold_emb<<<G4, 64, 0, stream>>>(Wih, Wemb, bemb, bih, bhh, flag, M0, M1, Beff);

  for (int t = 0; t < T_LEN; t++) {
    const ushort* ih = (t & 1) ? hB : hA;
    ushort* oh = (t & 1) ? hA : hB;
    lstm_step<<<512, 512, 0, stream>>>(ih, oh, d_out, c_state,
                                       wpk, M0, M1, Beff,
                                       obs, t, flag, (t == T_LEN - 1) ? 1 : 0);
  }
}